// Round 10
// baseline (404.981 us; speedup 1.0000x reference)
//
#include <hip/hip_runtime.h>

// out[b, f*TIME+t, e] = x[b, f*TIME+t, e] + pe_1d[f, e] + pe_1d[t, e]
// B=4, FREQ=256, TIME=512, E=512, fp32.
//
// Round 8 (kept): COMPACT-SWEEP mapping (grid-stride, stride = total
// threads) — instantaneous chip footprint is one contiguous 64 MiB window,
// uniform over HBM channels. Zero per-iteration pe loads: t invariant per
// thread (pt loaded once); f advances 64/iter -> pf advances by rotation
// with rot = pe[64] (exact table values), reset each batch.
//
// Round 9 (single lever): LOAD IS TEMPORAL; store stays nt.
// Ledger: r4 (nt both) = +3%; r7 (temporal store, nt load) = −6%
//   => nt-store ≈ +6%, nt-load ≈ −3% by additivity. Isolating it.

typedef float f32x4 __attribute__((ext_vector_type(4)));

constexpr int  B_    = 4;
constexpr int  FREQ_ = 256;
constexpr int  TIME_ = 512;
constexpr int  E_    = 512;
constexpr int  E4    = E_ / 4;                 // 128 float4 per row
constexpr int  ROWS  = FREQ_ * TIME_;          // 131072 rows per batch
constexpr long N4T   = (long)B_ * ROWS * E4;   // 2^26 total float4

constexpr int BLOCK    = 256;
constexpr int GRID     = 16384;
constexpr int NTHREADS = GRID * BLOCK;         // 2^22
constexpr int STRIDE   = NTHREADS;             // float4 units; = 32768 rows
constexpr int ITERS    = (int)(N4T / NTHREADS);        // 16
constexpr int ROWSTEP  = STRIDE / E4;                  // 32768 rows/iter
constexpr int ITERS_PER_BATCH = ROWS / ROWSTEP;        // 4
constexpr int FSTEP    = ROWSTEP / TIME_;              // f advances 64/iter

static_assert(ROWSTEP % TIME_ == 0, "t invariant per thread");
static_assert(ROWS % ROWSTEP == 0, "batch boundary aligns with iterations");
static_assert(ITERS == B_ * ITERS_PER_BATCH, "iter count");

__global__ void __launch_bounds__(BLOCK)
pe2d_add_kernel(const f32x4* __restrict__ x,
                const f32x4* __restrict__ pe,
                f32x4* __restrict__ out)
{
    const int i0  = blockIdx.x * BLOCK + threadIdx.x;  // < 2^22
    const int e4  = i0 & (E4 - 1);
    const int row = i0 >> 7;                           // < 32768
    const int t   = row & (TIME_ - 1);                 // invariant
    const int f0  = row >> 9;                          // < 64

    // one-time table loads (exact float32 table values)
    const f32x4 pt  = pe[t     * E4 + e4];             // time comp (invariant)
    const f32x4 pf0 = pe[f0    * E4 + e4];             // freq comp at f0
    const f32x4 rot = pe[FSTEP * E4 + e4];             // (sin 64d, cos 64d) pairs

    int i = i0;

    #pragma unroll
    for (int b = 0; b < B_; ++b) {
        f32x4 pf = pf0;                                // reset at batch boundary
        #pragma unroll
        for (int k = 0; k < ITERS_PER_BATCH; ++k) {
            f32x4 v = x[i];                            // TEMPORAL load (round-9 lever)
            v = v + pf + pt;
            __builtin_nontemporal_store(v, &out[i]);   // nt store (proven +6%)
            i += STRIDE;

            // advance freq component: f -> f+64 via 2D rotation per pair
            //   s' = s*cos + c*sin ; c' = c*cos - s*sin
            f32x4 np;
            np.x = pf.x * rot.y + pf.y * rot.x;
            np.y = pf.y * rot.y - pf.x * rot.x;
            np.z = pf.z * rot.w + pf.w * rot.z;
            np.w = pf.w * rot.w - pf.z * rot.z;
            pf = np;
        }
    }
}

extern "C" void kernel_launch(void* const* d_in, const int* in_sizes, int n_in,
                              void* d_out, int out_size, void* d_ws, size_t ws_size,
                              hipStream_t stream)
{
    const f32x4* x  = (const f32x4*)d_in[0];   // (B, FREQ*TIME, E) fp32
    const f32x4* pe = (const f32x4*)d_in[1];   // (512, E) fp32
    f32x4* out = (f32x4*)d_out;

    pe2d_add_kernel<<<GRID, BLOCK, 0, stream>>>(x, pe, out);
}

// Round 11
// 383.858 us; speedup vs baseline: 1.0550x; 1.0550x over previous
//
#include <hip/hip_runtime.h>

// out[b, f*TIME+t, e] = x[b, f*TIME+t, e] + pe_1d[f, e] + pe_1d[t, e]
// B=4, FREQ=256, TIME=512, E=512, fp32.
//
// FINAL CONFIG (= round 8, the measured best at 384 us / 5.59 TB/s):
//  - COMPACT-SWEEP mapping: grid-stride with stride = total threads; the
//    chip's instantaneous footprint is one contiguous 64 MiB window,
//    uniformly spread over HBM channels (copy-identical). [r8: +2.3%]
//  - nt LOAD + nt STORE on the one-touch x/out streams. [r7/r9 inversions:
//    temporal store −6%, temporal load −5%]
//  - Zero per-iteration pe loads: t is invariant per thread (pt loaded
//    once); f advances exactly 64/iter -> pf advances via 2D rotation with
//    rot = pe[64] (exact table values), reset to pf0 at each batch
//    boundary (max 3 steps -> err ~1e-6 << 0.147 threshold). [r6: neutral
//    vs L2 loads, kept for copy-identical memory behavior]
//  - Fine grid (16384 blocks x 256) for launch-tail smoothing. [r5: +2%]

typedef float f32x4 __attribute__((ext_vector_type(4)));

constexpr int  B_    = 4;
constexpr int  FREQ_ = 256;
constexpr int  TIME_ = 512;
constexpr int  E_    = 512;
constexpr int  E4    = E_ / 4;                 // 128 float4 per row
constexpr int  ROWS  = FREQ_ * TIME_;          // 131072 rows per batch
constexpr long N4T   = (long)B_ * ROWS * E4;   // 2^26 total float4

constexpr int BLOCK    = 256;
constexpr int GRID     = 16384;
constexpr int NTHREADS = GRID * BLOCK;         // 2^22
constexpr int STRIDE   = NTHREADS;             // float4 units; = 32768 rows
constexpr int ITERS    = (int)(N4T / NTHREADS);        // 16
constexpr int ROWSTEP  = STRIDE / E4;                  // 32768 rows/iter
constexpr int ITERS_PER_BATCH = ROWS / ROWSTEP;        // 4
constexpr int FSTEP    = ROWSTEP / TIME_;              // f advances 64/iter

static_assert(ROWSTEP % TIME_ == 0, "t invariant per thread");
static_assert(ROWS % ROWSTEP == 0, "batch boundary aligns with iterations");
static_assert(ITERS == B_ * ITERS_PER_BATCH, "iter count");

__global__ void __launch_bounds__(BLOCK)
pe2d_add_kernel(const f32x4* __restrict__ x,
                const f32x4* __restrict__ pe,
                f32x4* __restrict__ out)
{
    const int i0  = blockIdx.x * BLOCK + threadIdx.x;  // < 2^22
    const int e4  = i0 & (E4 - 1);
    const int row = i0 >> 7;                           // < 32768
    const int t   = row & (TIME_ - 1);                 // invariant
    const int f0  = row >> 9;                          // < 64

    // one-time table loads (exact float32 table values)
    const f32x4 pt  = pe[t     * E4 + e4];             // time comp (invariant)
    const f32x4 pf0 = pe[f0    * E4 + e4];             // freq comp at f0
    const f32x4 rot = pe[FSTEP * E4 + e4];             // (sin 64d, cos 64d) pairs

    int i = i0;

    #pragma unroll
    for (int b = 0; b < B_; ++b) {
        f32x4 pf = pf0;                                // reset at batch boundary
        #pragma unroll
        for (int k = 0; k < ITERS_PER_BATCH; ++k) {
            f32x4 v = __builtin_nontemporal_load(&x[i]);
            v = v + pf + pt;
            __builtin_nontemporal_store(v, &out[i]);
            i += STRIDE;

            // advance freq component: f -> f+64 via 2D rotation per pair
            //   s' = s*cos + c*sin ; c' = c*cos - s*sin
            f32x4 np;
            np.x = pf.x * rot.y + pf.y * rot.x;
            np.y = pf.y * rot.y - pf.x * rot.x;
            np.z = pf.z * rot.w + pf.w * rot.z;
            np.w = pf.w * rot.w - pf.z * rot.z;
            pf = np;
        }
    }
}

extern "C" void kernel_launch(void* const* d_in, const int* in_sizes, int n_in,
                              void* d_out, int out_size, void* d_ws, size_t ws_size,
                              hipStream_t stream)
{
    const f32x4* x  = (const f32x4*)d_in[0];   // (B, FREQ*TIME, E) fp32
    const f32x4* pe = (const f32x4*)d_in[1];   // (512, E) fp32
    f32x4* out = (f32x4*)d_out;

    pe2d_add_kernel<<<GRID, BLOCK, 0, stream>>>(x, pe, out);
}